// Round 7
// baseline (270.694 us; speedup 1.0000x reference)
//
#include <hip/hip_runtime.h>
#include <stdint.h>

// ---------------------------------------------------------------------------
// GCN block: 3 x [ h = leaky_relu(in @ W);  out = adj@h + h ]   (I folded OUT)
// B=64, N=4096, D=16.  GEMM M=4096 x C=1024 x K=4096, fp8 e4m3 MX-scaled
// mfma_scale_16x16x128 (unit scales), fp32 accum over FULL K per block.
// Round 13: r10's fused 4-launch structure (saved 56us non-gemm, measured)
// at r7's TLP (its gemm defect: 4 waves = 1 wave/SIMD, Occ 10%, 47.5us).
//  - gemm: 512 threads (8 waves = 2/SIMD, r7-equal TLP), 256 blocks, 128x128
//    tile, full K.  Wave tile 64n x 32c, acc[4][2].  Dbuf 64KB, counted
//    s_waitcnt vmcnt(4) + raw s_barrier (per-wave vmcnt covers own rows;
//    barrier makes it collective), setprio around MFMA.
//  - Epilogue (r10's verified formulas, width-adapted): u_lds 64KB aliases
//    the dbuf; ht 32KB separate; mode 0 writes hnc' + transposed hb8';
//    mode 1 writes fp32 out.  linear_fuse + add_out kernels stay deleted.
// 4 launches: prep, gemm(W1), gemm(W2), gemm(final).
// ws: adj8 16MB | hb8_a 4MB | hb8_b 4MB | hnc 8MB = 32MB
// ---------------------------------------------------------------------------

typedef float  f32x4  __attribute__((ext_vector_type(4)));
typedef unsigned short ushort8 __attribute__((ext_vector_type(8)));
typedef int    i32x4  __attribute__((ext_vector_type(4)));
typedef int    i32x8  __attribute__((ext_vector_type(8)));

typedef __attribute__((address_space(1))) void* as1p;
typedef __attribute__((address_space(3))) void* as3p;
#define GLOAD_LDS16(G, L) \
  __builtin_amdgcn_global_load_lds((as1p)(G), (as3p)(L), 16, 0, 0)

#define ADJ_SCALE 4096.0f
#define ADJ_DESCALE (1.0f / 4096.0f)
#define SCALE_ONE 0x7f7f7f7f  // e8m0 exponent 127 = 2^0 = 1.0 in every byte

__device__ __forceinline__ unsigned short f2bf(float f) {
  unsigned u = __float_as_uint(f);
  u += 0x7fffu + ((u >> 16) & 1u);  // RNE
  return (unsigned short)(u >> 16);
}
__device__ __forceinline__ float bf2f(unsigned short u) {
  return __uint_as_float(((unsigned)u) << 16);
}
// pack 4 fp32 -> 4 fp8 e4m3 bytes (RNE, saturating)
__device__ __forceinline__ int pk4_fp8(float a, float b, float c, float d) {
  int v = __builtin_amdgcn_cvt_pk_fp8_f32(a, b, 0, false);   // bytes 0,1
  v = __builtin_amdgcn_cvt_pk_fp8_f32(c, d, v, true);        // bytes 2,3
  return v;
}

// ---------------------------------------------------------------------------
// prep: role-split fusion of two independent memory-bound kernels.
//   bid <  1024 : layer-0 linear  h0 = leaky(x @ W0), tile 64n x 64c
//   bid >= 1024 : adj8 = e4m3(adj * 4096), 1 thread = 16 elements
// ---------------------------------------------------------------------------
__global__ void prep(const float* __restrict__ adj,
                     unsigned char* __restrict__ a8,
                     const float* __restrict__ x,
                     const float* __restrict__ W,
                     unsigned char* __restrict__ hb8,
                     unsigned short* __restrict__ hnc_out) {
  __shared__ float xs[64 * 65];
  __shared__ unsigned short ht[64 * 72];
  int bid = blockIdx.x;

  if (bid >= 1024) {
    // ---- adj quantize part ----
    size_t base = ((size_t)(bid - 1024) * 256 + threadIdx.x) * 16;
    const float4* src = (const float4*)(adj + base);
    float4 q0 = src[0], q1 = src[1], q2 = src[2], q3 = src[3];
    int4 o;
    o.x = pk4_fp8(q0.x * ADJ_SCALE, q0.y * ADJ_SCALE, q0.z * ADJ_SCALE, q0.w * ADJ_SCALE);
    o.y = pk4_fp8(q1.x * ADJ_SCALE, q1.y * ADJ_SCALE, q1.z * ADJ_SCALE, q1.w * ADJ_SCALE);
    o.z = pk4_fp8(q2.x * ADJ_SCALE, q2.y * ADJ_SCALE, q2.z * ADJ_SCALE, q2.w * ADJ_SCALE);
    o.w = pk4_fp8(q3.x * ADJ_SCALE, q3.y * ADJ_SCALE, q3.z * ADJ_SCALE, q3.w * ADJ_SCALE);
    *(int4*)(a8 + base) = o;
    return;
  }

  // ---- layer-0 linear part ----
  int n0 = (bid & 63) * 64, c0 = (bid >> 6) * 64;

  for (int i = threadIdx.x; i < 1024; i += 256) {
    int bs = i >> 8, rem = i & 255, nr = rem >> 2, d4 = rem & 3;
    float4 v = *(const float4*)(
        x + ((size_t)(c0 / 16 + bs) * 4096 + n0 + nr) * 16 + d4 * 4);
    float* dst = xs + nr * 65 + bs * 16 + d4 * 4;
    dst[0] = v.x; dst[1] = v.y; dst[2] = v.z; dst[3] = v.w;
  }
  __syncthreads();

  int n_l = threadIdx.x & 63, b_l = threadIdx.x >> 6;   // b_l 0..3
  float xv[16];
#pragma unroll
  for (int d = 0; d < 16; ++d) xv[d] = xs[n_l * 65 + b_l * 16 + d];
  float accv[16];
#pragma unroll
  for (int e = 0; e < 16; ++e) accv[e] = 0.f;
#pragma unroll
  for (int d = 0; d < 16; ++d)
#pragma unroll
    for (int e = 0; e < 16; ++e) accv[e] += xv[d] * W[d * 16 + e];

  ushort8 h0, h1;
#pragma unroll
  for (int e = 0; e < 16; ++e) {
    float a = accv[e] > 0.f ? accv[e] : 0.2f * accv[e];
    unsigned short hv = f2bf(a);
    ht[(b_l * 16 + e) * 72 + n_l] = hv;
    if (e < 8) h0[e] = hv; else h1[e - 8] = hv;
  }
  unsigned short* ho = hnc_out + (size_t)(n0 + n_l) * 1024 + c0 + b_l * 16;
  *(ushort8*)(ho)     = h0;
  *(ushort8*)(ho + 8) = h1;
  __syncthreads();

  for (int i = threadIdx.x; i < 512; i += 256) {
    int row = i >> 3, ch = i & 7;
    const unsigned short* s = ht + row * 72 + ch * 8;
    int2 v;
    v.x = pk4_fp8(bf2f(s[0]), bf2f(s[1]), bf2f(s[2]), bf2f(s[3]));
    v.y = pk4_fp8(bf2f(s[4]), bf2f(s[5]), bf2f(s[6]), bf2f(s[7]));
    *(int2*)(hb8 + (size_t)(c0 + row) * 4096 + n0 + ch * 8) = v;
  }
}

// ---------------------------------------------------------------------------
// gemm + fused next-layer linear (mode 0) or final output (mode 1).
// p[n][c] = (adj8[n0..][k] * hb8[c0..][k]) / 4096, full K per block.
// Grid 256 = 4mth x 8ct x 8xcd.  512 threads: 8 waves 2(wm) x 4(wn),
// wave tile 64n x 32c, acc[4][2].
// K-loop: dbuf gload_lds staging (wave w stages rows w*16..w*16+15, 2 insts
// per operand), XOR chunk swizzle phys = logical ^ (row&7), counted
// s_waitcnt vmcnt(4) + raw s_barrier; stage(it+2) after post-compute
// barrier; no vmcnt(0) in the main loop.  setprio(1) around MFMA.
// Epilogue: u_lds[128][128] fp32 (aliases dbuf, 64KB) + ht 32KB.
//   mode 0: u = acc/4096 + hnc; h' = leaky(u@Wn) per 16-group;
//           hnc <- h' bf16 (same addr, same thread), hb8o <- fp8 [c][n].
//   mode 1: out[(c>>4)*65536 + n*16 + (c&15)] = u  (fp32).
// ---------------------------------------------------------------------------
__global__ __launch_bounds__(512, 1)
void gemm_f8(const unsigned char* __restrict__ A,
             const unsigned char* __restrict__ B8,
             const float* __restrict__ Wn,
             unsigned short* __restrict__ hnc,
             unsigned char* __restrict__ hb8o,
             float* __restrict__ out,
             int mode) {
  const int K = 4096;
  __shared__ unsigned char smem[98304];   // dbuf 64KB (K-loop) | u_lds 64KB + ht 32KB (epilogue)
  unsigned char* a_s[2] = {smem,         smem + 16384};
  unsigned char* b_s[2] = {smem + 32768, smem + 49152};

  int tid = threadIdx.x, wave = tid >> 6, lane = tid & 63;

  int lin = blockIdx.x;                   // 256 blocks
  int xcd = lin & 7, g = lin >> 3;
  int mth = g & 3, ct = g >> 2;           // ct 0..7
  int mt = mth * 8 + xcd;                 // 0..31
  int n0 = mt * 128, c0 = ct * 128;

  // staging: wave w covers rows w*16..w*16+15 (2 insts each operand)
  int l8 = lane >> 3, lc = lane & 7;
  int swc = lc ^ l8;                      // logical chunk fetched into phys lc
  const unsigned char* gA[2];
  const unsigned char* gB[2];
#pragma unroll
  for (int j = 0; j < 2; ++j) {
    int r = wave * 16 + j * 8 + l8;
    gA[j] = A  + (size_t)(n0 + r) * K + swc * 16;
    gB[j] = B8 + (size_t)(c0 + r) * K + swc * 16;
  }

  int i16 = lane & 15, q = lane >> 4;
  int wm = wave >> 2, wn = wave & 3;      // 2 x 4
  int sw7 = i16 & 7;
  int pc0 = ((2 * q) ^ sw7) * 16;         // phys offset of logical chunk 2q
  int pc1 = ((2 * q + 1) ^ sw7) * 16;     // phys offset of logical chunk 2q+1

#define STAGE(buf, it)                                                \
  do {                                                                \
    int k0_ = (it) * 128;                                             \
    _Pragma("unroll")                                                 \
    for (int j = 0; j < 2; ++j) {                                     \
      GLOAD_LDS16(gA[j] + k0_, a_s[buf] + (wave * 16 + j * 8) * 128); \
      GLOAD_LDS16(gB[j] + k0_, b_s[buf] + (wave * 16 + j * 8) * 128); \
    }                                                                 \
  } while (0)

#define COMPUTE(buf)                                                  \
  do {                                                                \
    i32x8 bv[2];                                                      \
    _Pragma("unroll")                                                 \
    for (int u = 0; u < 2; ++u) {                                     \
      const unsigned char* bp = b_s[buf] + (wn * 32 + u * 16 + i16) * 128; \
      i32x4 blo = *(const i32x4*)(bp + pc0);                          \
      i32x4 bhi = *(const i32x4*)(bp + pc1);                          \
      bv[u] = __builtin_shufflevector(blo, bhi, 0, 1, 2, 3, 4, 5, 6, 7); \
    }                                                                 \
    __builtin_amdgcn_s_setprio(1);                                    \
    _Pragma("unroll")                                                 \
    for (int t = 0; t < 4; ++t) {                                     \
      const unsigned char* ap = a_s[buf] + (wm * 64 + t * 16 + i16) * 128; \
      i32x4 alo = *(const i32x4*)(ap + pc0);                          \
      i32x4 ahi = *(const i32x4*)(ap + pc1);                          \
      i32x8 av = __builtin_shufflevector(alo, ahi, 0, 1, 2, 3, 4, 5, 6, 7); \
      _Pragma("unroll")                                               \
      for (int u = 0; u < 2; ++u)                                     \
        acc[t][u] = __builtin_amdgcn_mfma_scale_f32_16x16x128_f8f6f4( \
            av, bv[u], acc[t][u], 0, 0, 0, SCALE_ONE, 0, SCALE_ONE);  \
    }                                                                 \
    __builtin_amdgcn_s_setprio(0);                                    \
  } while (0)

#define WAITVM4() asm volatile("s_waitcnt vmcnt(4)" ::: "memory")
#define WAITVM0() asm volatile("s_waitcnt vmcnt(0)" ::: "memory")
#define BARX() do { asm volatile("" ::: "memory");                    \
                    __builtin_amdgcn_s_barrier();                     \
                    asm volatile("" ::: "memory"); } while (0)

  f32x4 acc[4][2] = {};

  // prologue: two tiles in flight (8 loads/wave)
  STAGE(0, 0);
  STAGE(1, 1);

  // per iter: vmcnt(4) retires own-stage(it); barrier makes it collective
  // across waves; compute; barrier (all reads done); re-stage the buffer.
  for (int itb = 0; itb < 30; itb += 2) {
    WAITVM4(); BARX(); COMPUTE(0); BARX(); STAGE(0, itb + 2);
    WAITVM4(); BARX(); COMPUTE(1); BARX(); STAGE(1, itb + 3);
  }
  // loop computed tiles 0..29, staged through tile 31.
  WAITVM4(); BARX(); COMPUTE(0);          // it = 30
  WAITVM0(); BARX(); COMPUTE(1);          // it = 31

#undef STAGE
#undef COMPUTE
#undef WAITVM4
#undef WAITVM0
#undef BARX

  // -------------------------------------------------------------------------
  // epilogue
  // -------------------------------------------------------------------------
  __syncthreads();                        // all compute reads done; alias smem
  float* u_lds = (float*)smem;                           // 64 KB [128][128]
  unsigned short* ht = (unsigned short*)(smem + 65536);  // 32 KB [128][128]

  // deposit raw acc fp32 with XOR-16 column swizzle
#pragma unroll
  for (int t = 0; t < 4; ++t)
#pragma unroll
    for (int u = 0; u < 2; ++u)
#pragma unroll
      for (int i = 0; i < 4; ++i) {
        int n_l = wm * 64 + t * 16 + q * 4 + i;
        int c_l = wn * 32 + u * 16 + i16;
        u_lds[n_l * 128 + (c_l ^ (((n_l >> 2) & 1) << 4))] = acc[t][u][i];
      }
  __syncthreads();

  if (mode == 0) {
    for (int s = 0; s < 2; ++s) {
      int item = s * 512 + tid;                  // 1024 (n, group) items
      int n_l = item & 127, gi = item >> 7;      // gi 0..7
      int pg = gi ^ ((n_l >> 2) & 1);
      const float* up = u_lds + n_l * 128 + pg * 16;
      size_t gb = (size_t)(n0 + n_l) * 1024 + c0 + gi * 16;
      ushort8 hn0 = *(const ushort8*)(hnc + gb);
      ushort8 hn1 = *(const ushort8*)(hnc + gb + 8);
      float ud[16];
#pragma unroll
      for (int d = 0; d < 8; ++d) {
        ud[d]     = up[d]     * ADJ_DESCALE + bf2f(hn0[d]);
        ud[d + 8] = up[d + 8] * ADJ_DESCALE + bf2f(hn1[d]);
      }
      float hv[16];
#pragma unroll
      for (int e = 0; e < 16; ++e) hv[e] = 0.f;
#pragma unroll
      for (int d = 0; d < 16; ++d)
#pragma unroll
        for (int e = 0; e < 16; ++e) hv[e] += ud[d] * Wn[d * 16 + e];
      ushort8 o0, o1;
#pragma unroll
      for (int e = 0; e < 16; ++e) {
        float a = hv[e] > 0.f ? hv[e] : 0.2f * hv[e];
        unsigned short hb = f2bf(a);
        if (e < 8) o0[e] = hb; else o1[e - 8] = hb;
        int cr = gi * 16 + e;                    // transposed stash, swizzled
        ht[cr * 128 + (((n_l >> 3) ^ (cr & 15)) << 3) + (n_l & 7)] = hb;
      }
      *(ushort8*)(hnc + gb)     = o0;            // h' identity term (in-place)
      *(ushort8*)(hnc + gb + 8) = o1;
    }
    __syncthreads();
    // transposed fp8 store: hb8o[c][n]
    for (int s = 0; s < 4; ++s) {
      int item = s * 512 + tid;                  // 2048 = 128c x 16 chunks
      int c_l = item >> 4, n8 = item & 15;
      const unsigned short* hp = ht + c_l * 128 + ((n8 ^ (c_l & 15)) << 3);
      int2 v;
      v.x = pk4_fp8(bf2f(hp[0]), bf2f(hp[1]), bf2f(hp[2]), bf2f(hp[3]));
      v.y = pk4_fp8(bf2f(hp[4]), bf2f(hp[5]), bf2f(hp[6]), bf2f(hp[7]));
      *(int2*)(hb8o + (size_t)(c0 + c_l) * 4096 + n0 + n8 * 8) = v;
    }
  } else {
    // final: out fp32 (b,n,d), b = c/16, d = c&15
    for (int s = 0; s < 2; ++s) {
      int item = s * 512 + tid;
      int n_l = item & 127, gi = item >> 7;
      int pg = gi ^ ((n_l >> 2) & 1);
      const float* up = u_lds + n_l * 128 + pg * 16;
      size_t gb = (size_t)(n0 + n_l) * 1024 + c0 + gi * 16;
      ushort8 hn0 = *(const ushort8*)(hnc + gb);
      ushort8 hn1 = *(const ushort8*)(hnc + gb + 8);
      float v[16];
#pragma unroll
      for (int d = 0; d < 8; ++d) {
        v[d]     = up[d]     * ADJ_DESCALE + bf2f(hn0[d]);
        v[d + 8] = up[d + 8] * ADJ_DESCALE + bf2f(hn1[d]);
      }
      int bb = (c0 >> 4) + gi;
      float* op = out + (size_t)bb * 65536 + (size_t)(n0 + n_l) * 16;
      *(float4*)(op)      = float4{v[0],  v[1],  v[2],  v[3]};
      *(float4*)(op + 4)  = float4{v[4],  v[5],  v[6],  v[7]};
      *(float4*)(op + 8)  = float4{v[8],  v[9],  v[10], v[11]};
      *(float4*)(op + 12) = float4{v[12], v[13], v[14], v[15]};
    }
  }
}

// ---------------------------------------------------------------------------
extern "C" void kernel_launch(void* const* d_in, const int* in_sizes, int n_in,
                              void* d_out, int out_size, void* d_ws, size_t ws_size,
                              hipStream_t stream) {
  const float* x   = (const float*)d_in[0];
  const float* adj = (const float*)d_in[1];
  // d_in[2] = Identity (handled as the +h_nc term)
  const float* W0  = (const float*)d_in[3];
  const float* W1  = (const float*)d_in[4];
  const float* W2  = (const float*)d_in[5];
  float* out = (float*)d_out;

  char* ws = (char*)d_ws;
  unsigned char*  adj8  = (unsigned char*)ws;                  // 16 MiB
  unsigned char*  hb8_a = (unsigned char*)(ws + 16777216);     //  4 MiB
  unsigned char*  hb8_b = (unsigned char*)(ws + 20971520);     //  4 MiB
  unsigned short* hnc   = (unsigned short*)(ws + 25165824);    //  8 MiB

  // layer 0 linear + adj quantize fused (independent, both memory-bound)
  prep<<<5120, 256, 0, stream>>>(adj, adj8, x, W0, hb8_a, hnc);
  // layer 0 gemm + fused layer-1 linear
  gemm_f8<<<256, 512, 0, stream>>>(adj8, hb8_a, W1, hnc, hb8_b, out, 0);
  // layer 1 gemm + fused layer-2 linear
  gemm_f8<<<256, 512, 0, stream>>>(adj8, hb8_b, W2, hnc, hb8_a, out, 0);
  // layer 2 gemm + final output
  gemm_f8<<<256, 512, 0, stream>>>(adj8, hb8_a, (const float*)nullptr,
                                   hnc, (unsigned char*)nullptr, out, 1);
}

// Round 8
// 251.469 us; speedup vs baseline: 1.0765x; 1.0765x over previous
//
#include <hip/hip_runtime.h>
#include <stdint.h>

// ---------------------------------------------------------------------------
// GCN block: 3 x [ h = leaky_relu(in @ W);  out = adj@h + h ]   (I folded OUT)
// B=64, N=4096, D=16.  GEMM M=4096 x C=1024 x K=4096, fp8 e4m3 MX-scaled
// mfma_scale_16x16x128 (unit scales), fp32 accum over FULL K per block.
// Round 14: measured across r7..r13, gemm time tracks ONE variable:
// independent barrier groups/CU (2 -> 23us, 1 -> 48us; schedule + waves/SIMD
// irrelevant).  One block = one barrier group = every stage-wait stalls the
// whole CU (~550cyc compute vs ~1500cyc load latency).  So: keep the fused
// 4-launch structure (measured -56us non-gemm) but split each output tile
// into TWO 128n x 64c full-K blocks -> 512 blocks x 256 thr = 2 indep
// blocks/CU.  64 cols = 4 complete 16-ch groups -> linear fusion intact.
// Per block: A dbuf 2x16KB + B dbuf 2x8KB = 48KB; 4 waves 2x2, acc[4][2];
// 6 loads/wave/stage, counted vmcnt(6) + raw s_barrier; setprio on MFMA.
// Epilogue aliases smem: u_lds[128][64] fp32 32KB + ht[64][128] bf16 16KB.
// 4 launches: prep, gemm(W1), gemm(W2), gemm(final).
// ws: adj8 16MB | hb8_a 4MB | hb8_b 4MB | hnc 8MB = 32MB
// ---------------------------------------------------------------------------

typedef float  f32x4  __attribute__((ext_vector_type(4)));
typedef unsigned short ushort8 __attribute__((ext_vector_type(8)));
typedef int    i32x4  __attribute__((ext_vector_type(4)));
typedef int    i32x8  __attribute__((ext_vector_type(8)));

typedef __attribute__((address_space(1))) void* as1p;
typedef __attribute__((address_space(3))) void* as3p;
#define GLOAD_LDS16(G, L) \
  __builtin_amdgcn_global_load_lds((as1p)(G), (as3p)(L), 16, 0, 0)

#define ADJ_SCALE 4096.0f
#define ADJ_DESCALE (1.0f / 4096.0f)
#define SCALE_ONE 0x7f7f7f7f  // e8m0 exponent 127 = 2^0 = 1.0 in every byte

__device__ __forceinline__ unsigned short f2bf(float f) {
  unsigned u = __float_as_uint(f);
  u += 0x7fffu + ((u >> 16) & 1u);  // RNE
  return (unsigned short)(u >> 16);
}
__device__ __forceinline__ float bf2f(unsigned short u) {
  return __uint_as_float(((unsigned)u) << 16);
}
// pack 4 fp32 -> 4 fp8 e4m3 bytes (RNE, saturating)
__device__ __forceinline__ int pk4_fp8(float a, float b, float c, float d) {
  int v = __builtin_amdgcn_cvt_pk_fp8_f32(a, b, 0, false);   // bytes 0,1
  v = __builtin_amdgcn_cvt_pk_fp8_f32(c, d, v, true);        // bytes 2,3
  return v;
}

// ---------------------------------------------------------------------------
// prep: role-split fusion of two independent memory-bound kernels.
//   bid <  1024 : layer-0 linear  h0 = leaky(x @ W0), tile 64n x 64c
//   bid >= 1024 : adj8 = e4m3(adj * 4096), 1 thread = 16 elements
// ---------------------------------------------------------------------------
__global__ void prep(const float* __restrict__ adj,
                     unsigned char* __restrict__ a8,
                     const float* __restrict__ x,
                     const float* __restrict__ W,
                     unsigned char* __restrict__ hb8,
                     unsigned short* __restrict__ hnc_out) {
  __shared__ float xs[64 * 65];
  __shared__ unsigned short ht[64 * 72];
  int bid = blockIdx.x;

  if (bid >= 1024) {
    // ---- adj quantize part ----
    size_t base = ((size_t)(bid - 1024) * 256 + threadIdx.x) * 16;
    const float4* src = (const float4*)(adj + base);
    float4 q0 = src[0], q1 = src[1], q2 = src[2], q3 = src[3];
    int4 o;
    o.x = pk4_fp8(q0.x * ADJ_SCALE, q0.y * ADJ_SCALE, q0.z * ADJ_SCALE, q0.w * ADJ_SCALE);
    o.y = pk4_fp8(q1.x * ADJ_SCALE, q1.y * ADJ_SCALE, q1.z * ADJ_SCALE, q1.w * ADJ_SCALE);
    o.z = pk4_fp8(q2.x * ADJ_SCALE, q2.y * ADJ_SCALE, q2.z * ADJ_SCALE, q2.w * ADJ_SCALE);
    o.w = pk4_fp8(q3.x * ADJ_SCALE, q3.y * ADJ_SCALE, q3.z * ADJ_SCALE, q3.w * ADJ_SCALE);
    *(int4*)(a8 + base) = o;
    return;
  }

  // ---- layer-0 linear part ----
  int n0 = (bid & 63) * 64, c0 = (bid >> 6) * 64;

  for (int i = threadIdx.x; i < 1024; i += 256) {
    int bs = i >> 8, rem = i & 255, nr = rem >> 2, d4 = rem & 3;
    float4 v = *(const float4*)(
        x + ((size_t)(c0 / 16 + bs) * 4096 + n0 + nr) * 16 + d4 * 4);
    float* dst = xs + nr * 65 + bs * 16 + d4 * 4;
    dst[0] = v.x; dst[1] = v.y; dst[2] = v.z; dst[3] = v.w;
  }
  __syncthreads();

  int n_l = threadIdx.x & 63, b_l = threadIdx.x >> 6;   // b_l 0..3
  float xv[16];
#pragma unroll
  for (int d = 0; d < 16; ++d) xv[d] = xs[n_l * 65 + b_l * 16 + d];
  float accv[16];
#pragma unroll
  for (int e = 0; e < 16; ++e) accv[e] = 0.f;
#pragma unroll
  for (int d = 0; d < 16; ++d)
#pragma unroll
    for (int e = 0; e < 16; ++e) accv[e] += xv[d] * W[d * 16 + e];

  ushort8 h0, h1;
#pragma unroll
  for (int e = 0; e < 16; ++e) {
    float a = accv[e] > 0.f ? accv[e] : 0.2f * accv[e];
    unsigned short hv = f2bf(a);
    ht[(b_l * 16 + e) * 72 + n_l] = hv;
    if (e < 8) h0[e] = hv; else h1[e - 8] = hv;
  }
  unsigned short* ho = hnc_out + (size_t)(n0 + n_l) * 1024 + c0 + b_l * 16;
  *(ushort8*)(ho)     = h0;
  *(ushort8*)(ho + 8) = h1;
  __syncthreads();

  for (int i = threadIdx.x; i < 512; i += 256) {
    int row = i >> 3, ch = i & 7;
    const unsigned short* s = ht + row * 72 + ch * 8;
    int2 v;
    v.x = pk4_fp8(bf2f(s[0]), bf2f(s[1]), bf2f(s[2]), bf2f(s[3]));
    v.y = pk4_fp8(bf2f(s[4]), bf2f(s[5]), bf2f(s[6]), bf2f(s[7]));
    *(int2*)(hb8 + (size_t)(c0 + row) * 4096 + n0 + ch * 8) = v;
  }
}

// ---------------------------------------------------------------------------
// gemm + fused next-layer linear (mode 0) or final output (mode 1).
// p[n][c] = (adj8[n0..][k] * hb8[c0..][k]) / 4096, full K per block.
// Tile 128n x 64c.  Grid 512 = 4mth x 16ct x 8xcd (xcd = lin&7 -> all 16
// ct-consumers of one A slice share an XCD L2).  256 thr, 4 waves 2x2,
// wave tile 64n x 32c, acc[4][2].
// K-loop: dbuf, XOR chunk swizzle phys = logical ^ (row&7); 6 gload_lds
// per wave per stage (A 4, B 2); counted s_waitcnt vmcnt(6) + raw
// s_barrier; stage(it+2) after the post-compute barrier; no vmcnt(0) in
// the main loop; setprio(1) around the MFMA cluster.
// Epilogue (aliases smem): u_lds[128][64] fp32 (XOR-16 col swizzle) +
// ht[64][128] bf16.
//   mode 0: u = acc/4096 + hnc; h' = leaky(u@Wn) per 16-group;
//           hnc <- h' bf16 (in-place, own tile), hb8o <- fp8 [c][n].
//   mode 1: out[(c>>4)*65536 + n*16 + (c&15)] = u  (fp32).
// ---------------------------------------------------------------------------
__global__ __launch_bounds__(256)
void gemm_f8(const unsigned char* __restrict__ A,
             const unsigned char* __restrict__ B8,
             const float* __restrict__ Wn,
             unsigned short* __restrict__ hnc,
             unsigned char* __restrict__ hb8o,
             float* __restrict__ out,
             int mode) {
  const int K = 4096;
  __shared__ unsigned char smem[49152];   // A 2x16KB | B 2x8KB
  unsigned char* a_s[2] = {smem,         smem + 16384};
  unsigned char* b_s[2] = {smem + 32768, smem + 40960};

  int tid = threadIdx.x, wave = tid >> 6, lane = tid & 63;

  int lin = blockIdx.x;                   // 512 blocks
  int xcd = lin & 7, g = lin >> 3;
  int mth = g & 3, ct = g >> 2;           // ct 0..15
  int mt = mth * 8 + xcd;                 // 0..31
  int n0 = mt * 128, c0 = ct * 64;

  // staging: A wave w rows w*32..+31 (4 insts); B wave w rows w*16..+15 (2)
  int l8 = lane >> 3, lc = lane & 7;
  int swc = lc ^ l8;                      // logical chunk fetched into phys lc
  const unsigned char* gA[4];
  const unsigned char* gB[2];
#pragma unroll
  for (int j = 0; j < 4; ++j)
    gA[j] = A + (size_t)(n0 + wave * 32 + j * 8 + l8) * K + swc * 16;
#pragma unroll
  for (int j = 0; j < 2; ++j)
    gB[j] = B8 + (size_t)(c0 + wave * 16 + j * 8 + l8) * K + swc * 16;

  int i16 = lane & 15, q = lane >> 4;
  int wm = wave >> 1, wn = wave & 1;      // 2 x 2
  int sw7 = i16 & 7;
  int pc0 = ((2 * q) ^ sw7) * 16;         // phys offset of logical chunk 2q
  int pc1 = ((2 * q + 1) ^ sw7) * 16;     // phys offset of logical chunk 2q+1

#define STAGE(buf, it)                                                \
  do {                                                                \
    int k0_ = (it) * 128;                                             \
    _Pragma("unroll")                                                 \
    for (int j = 0; j < 4; ++j)                                       \
      GLOAD_LDS16(gA[j] + k0_, a_s[buf] + (wave * 32 + j * 8) * 128); \
    _Pragma("unroll")                                                 \
    for (int j = 0; j < 2; ++j)                                       \
      GLOAD_LDS16(gB[j] + k0_, b_s[buf] + (wave * 16 + j * 8) * 128); \
  } while (0)

#define COMPUTE(buf)                                                  \
  do {                                                                \
    i32x8 bv[2];                                                      \
    _Pragma("unroll")                                                 \
    for (int u = 0; u < 2; ++u) {                                     \
      const unsigned char* bp = b_s[buf] + (wn * 32 + u * 16 + i16) * 128; \
      i32x4 blo = *(const i32x4*)(bp + pc0);                          \
      i32x4 bhi = *(const i32x4*)(bp + pc1);                          \
      bv[u] = __builtin_shufflevector(blo, bhi, 0, 1, 2, 3, 4, 5, 6, 7); \
    }                                                                 \
    __builtin_amdgcn_s_setprio(1);                                    \
    _Pragma("unroll")                                                 \
    for (int t = 0; t < 4; ++t) {                                     \
      const unsigned char* ap = a_s[buf] + (wm * 64 + t * 16 + i16) * 128; \
      i32x4 alo = *(const i32x4*)(ap + pc0);                          \
      i32x4 ahi = *(const i32x4*)(ap + pc1);                          \
      i32x8 av = __builtin_shufflevector(alo, ahi, 0, 1, 2, 3, 4, 5, 6, 7); \
      _Pragma("unroll")                                               \
      for (int u = 0; u < 2; ++u)                                     \
        acc[t][u] = __builtin_amdgcn_mfma_scale_f32_16x16x128_f8f6f4( \
            av, bv[u], acc[t][u], 0, 0, 0, SCALE_ONE, 0, SCALE_ONE);  \
    }                                                                 \
    __builtin_amdgcn_s_setprio(0);                                    \
  } while (0)

#define WAITVM6() asm volatile("s_waitcnt vmcnt(6)" ::: "memory")
#define WAITVM0() asm volatile("s_waitcnt vmcnt(0)" ::: "memory")
#define BARX() do { asm volatile("" ::: "memory");                    \
                    __builtin_amdgcn_s_barrier();                     \
                    asm volatile("" ::: "memory"); } while (0)

  f32x4 acc[4][2] = {};

  // prologue: two tiles in flight (12 loads/wave)
  STAGE(0, 0);
  STAGE(1, 1);

  for (int itb = 0; itb < 30; itb += 2) {
    WAITVM6(); BARX(); COMPUTE(0); BARX(); STAGE(0, itb + 2);
    WAITVM6(); BARX(); COMPUTE(1); BARX(); STAGE(1, itb + 3);
  }
  // loop computed tiles 0..29, staged through tile 31.
  WAITVM6(); BARX(); COMPUTE(0);          // it = 30
  WAITVM0(); BARX(); COMPUTE(1);          // it = 31

#undef STAGE
#undef COMPUTE
#undef WAITVM6
#undef WAITVM0
#undef BARX

  // -------------------------------------------------------------------------
  // epilogue
  // -------------------------------------------------------------------------
  __syncthreads();                        // all compute reads done; alias smem
  float* u_lds = (float*)smem;                           // 32 KB [128][64]
  unsigned short* ht = (unsigned short*)(smem + 32768);  // 16 KB [64][128]

  // deposit raw acc fp32 with XOR-16 column swizzle (<=2-way)
#pragma unroll
  for (int t = 0; t < 4; ++t)
#pragma unroll
    for (int u = 0; u < 2; ++u)
#pragma unroll
      for (int i = 0; i < 4; ++i) {
        int n_l = wm * 64 + t * 16 + q * 4 + i;
        int c_l = wn * 32 + u * 16 + i16;
        u_lds[n_l * 64 + (c_l ^ (((n_l >> 2) & 1) << 4))] = acc[t][u][i];
      }
  __syncthreads();

  if (mode == 0) {
    for (int s = 0; s < 2; ++s) {
      int item = s * 256 + tid;                  // 512 (n, group) items
      int n_l = item & 127, gi = item >> 7;      // gi 0..3
      int pg = gi ^ ((n_l >> 2) & 1);
      const float* up = u_lds + n_l * 64 + pg * 16;
      size_t gb = (size_t)(n0 + n_l) * 1024 + c0 + gi * 16;
      ushort8 hn0 = *(const ushort8*)(hnc + gb);
      ushort8 hn1 = *(const ushort8*)(hnc + gb + 8);
      float ud[16];
#pragma unroll
      for (int d = 0; d < 8; ++d) {
        ud[d]     = up[d]     * ADJ_DESCALE + bf2f(hn0[d]);
        ud[d + 8] = up[d + 8] * ADJ_DESCALE + bf2f(hn1[d]);
      }
      float hv[16];
#pragma unroll
      for (int e = 0; e < 16; ++e) hv[e] = 0.f;
#pragma unroll
      for (int d = 0; d < 16; ++d)
#pragma unroll
        for (int e = 0; e < 16; ++e) hv[e] += ud[d] * Wn[d * 16 + e];
      ushort8 o0, o1;
#pragma unroll
      for (int e = 0; e < 16; ++e) {
        float a = hv[e] > 0.f ? hv[e] : 0.2f * hv[e];
        unsigned short hb = f2bf(a);
        if (e < 8) o0[e] = hb; else o1[e - 8] = hb;
        int cr = gi * 16 + e;                    // 0..63, transposed stash
        ht[cr * 128 + (((n_l >> 3) ^ (cr & 15)) << 3) + (n_l & 7)] = hb;
      }
      *(ushort8*)(hnc + gb)     = o0;            // h' identity term (in-place)
      *(ushort8*)(hnc + gb + 8) = o1;
    }
    __syncthreads();
    // transposed fp8 store: hb8o[c][n]
    for (int s = 0; s < 4; ++s) {
      int item = s * 256 + tid;                  // 1024 = 64c x 16 chunks
      int c_l = item >> 4, n8 = item & 15;
      const unsigned short* hp = ht + c_l * 128 + ((n8 ^ (c_l & 15)) << 3);
      int2 v;
      v.x = pk4_fp8(bf2f(hp[0]), bf2f(hp[1]), bf2f(hp[2]), bf2f(hp[3]));
      v.y = pk4_fp8(bf2f(hp[4]), bf2f(hp[5]), bf2f(hp[6]), bf2f(hp[7]));
      *(int2*)(hb8o + (size_t)(c0 + c_l) * 4096 + n0 + n8 * 8) = v;
    }
  } else {
    // final: out fp32 (b,n,d), b = c/16, d = c&15
    for (int s = 0; s < 2; ++s) {
      int item = s * 256 + tid;
      int n_l = item & 127, gi = item >> 7;      // gi 0..3
      int pg = gi ^ ((n_l >> 2) & 1);
      const float* up = u_lds + n_l * 64 + pg * 16;
      size_t gb = (size_t)(n0 + n_l) * 1024 + c0 + gi * 16;
      ushort8 hn0 = *(const ushort8*)(hnc + gb);
      ushort8 hn1 = *(const ushort8*)(hnc + gb + 8);
      float v[16];
#pragma unroll
      for (int d = 0; d < 8; ++d) {
        v[d]     = up[d]     * ADJ_DESCALE + bf2f(hn0[d]);
        v[d + 8] = up[d + 8] * ADJ_DESCALE + bf2f(hn1[d]);
      }
      int bb = (c0 >> 4) + gi;                   // ct*4 + gi
      float* op = out + (size_t)bb * 65536 + (size_t)(n0 + n_l) * 16;
      *(float4*)(op)      = float4{v[0],  v[1],  v[2],  v[3]};
      *(float4*)(op + 4)  = float4{v[4],  v[5],  v[6],  v[7]};
      *(float4*)(op + 8)  = float4{v[8],  v[9],  v[10], v[11]};
      *(float4*)(op + 12) = float4{v[12], v[13], v[14], v[15]};
    }
  }
}

// ---------------------------------------------------------------------------
extern "C" void kernel_launch(void* const* d_in, const int* in_sizes, int n_in,
                              void* d_out, int out_size, void* d_ws, size_t ws_size,
                              hipStream_t stream) {
  const float* x   = (const float*)d_in[0];
  const float* adj = (const float*)d_in[1];
  // d_in[2] = Identity (handled as the +h_nc term)
  const float* W0  = (const float*)d_in[3];
  const float* W1  = (const float*)d_in[4];
  const float* W2  = (const float*)d_in[5];
  float* out = (float*)d_out;

  char* ws = (char*)d_ws;
  unsigned char*  adj8  = (unsigned char*)ws;                  // 16 MiB
  unsigned char*  hb8_a = (unsigned char*)(ws + 16777216);     //  4 MiB
  unsigned char*  hb8_b = (unsigned char*)(ws + 20971520);     //  4 MiB
  unsigned short* hnc   = (unsigned short*)(ws + 25165824);    //  8 MiB

  // layer 0 linear + adj quantize fused (independent, both memory-bound)
  prep<<<5120, 256, 0, stream>>>(adj, adj8, x, W0, hb8_a, hnc);
  // layer 0 gemm + fused layer-1 linear
  gemm_f8<<<512, 256, 0, stream>>>(adj8, hb8_a, W1, hnc, hb8_b, out, 0);
  // layer 1 gemm + fused layer-2 linear
  gemm_f8<<<512, 256, 0, stream>>>(adj8, hb8_b, W2, hnc, hb8_a, out, 0);
  // layer 2 gemm + final output
  gemm_f8<<<512, 256, 0, stream>>>(adj8, hb8_a, (const float*)nullptr,
                                   hnc, (unsigned char*)nullptr, out, 1);
}

// Round 9
// 244.321 us; speedup vs baseline: 1.1079x; 1.0293x over previous
//
#include <hip/hip_runtime.h>
#include <stdint.h>

// ---------------------------------------------------------------------------
// GCN block: 3 x [ h = leaky_relu(in @ W);  out = adj@h + h ]   (I folded OUT)
// B=64, N=4096, D=16.  GEMM M=4096 x C=1024 x K=4096 in FP8 e4m3, fp32 accum,
// MX-scaled mfma_scale_16x16x128 with unit scales.
// Round 15: r7..r14 regression isolated the law:
//   gemm = block-iters/CU x 1450cyc (2 blocks/CU) or 3100cyc (1 block/CU),
// independent of bytes/schedule/depth -> the per-iter serial convoy
// (barrier -> ds_read burst -> lgkm -> MFMA -> barrier) is the cost; a 2nd
// independent barrier group overlaps it 2.1x.  This round: minimum
// block-iters/CU (ks-split 128^2 x K2048, 16 iters, 512 blocks) PLUS
// 4 waves/SIMD in 2 independent groups: 512 thr/block (8 waves, wave tile
// 64n x 32c, acc[4][2]), 2 blocks/CU (LDS 64KB x2 = 128 <= 160).
// Counted vmcnt(4) + raw s_barrier (r12's proven-safe schedule), setprio.
// prep / linear_fuse / add_out byte-identical to r12 (passed).
// ws: adj8 16MB | hb8 4MB | h_nc 8MB | p0 8MB | p1 8MB = 44MB
// ---------------------------------------------------------------------------

typedef float  f32x4  __attribute__((ext_vector_type(4)));
typedef unsigned short ushort8 __attribute__((ext_vector_type(8)));
typedef int    i32x4  __attribute__((ext_vector_type(4)));
typedef int    i32x8  __attribute__((ext_vector_type(8)));

typedef __attribute__((address_space(1))) void* as1p;
typedef __attribute__((address_space(3))) void* as3p;
#define GLOAD_LDS16(G, L) \
  __builtin_amdgcn_global_load_lds((as1p)(G), (as3p)(L), 16, 0, 0)

#define P_ELEMS 4194304       // elems per partial buffer (4096*1024)
#define ADJ_SCALE 4096.0f
#define ADJ_DESCALE (1.0f / 4096.0f)
#define SCALE_ONE 0x7f7f7f7f  // e8m0 exponent 127 = 2^0 = 1.0 in every byte

__device__ __forceinline__ unsigned short f2bf(float f) {
  unsigned u = __float_as_uint(f);
  u += 0x7fffu + ((u >> 16) & 1u);  // RNE
  return (unsigned short)(u >> 16);
}
__device__ __forceinline__ float bf2f(unsigned short u) {
  return __uint_as_float(((unsigned)u) << 16);
}
// pack 4 fp32 -> 4 fp8 e4m3 bytes (RNE, saturating)
__device__ __forceinline__ int pk4_fp8(float a, float b, float c, float d) {
  int v = __builtin_amdgcn_cvt_pk_fp8_f32(a, b, 0, false);   // bytes 0,1
  v = __builtin_amdgcn_cvt_pk_fp8_f32(c, d, v, true);        // bytes 2,3
  return v;
}

// ---------------------------------------------------------------------------
// prep: role-split fusion of two independent memory-bound kernels.
//   bid <  1024 : layer-0 linear  h0 = leaky(x @ W0), tile 64n x 64c
//   bid >= 1024 : adj8 = e4m3(adj * 4096), 1 thread = 16 elements
// ---------------------------------------------------------------------------
__global__ void prep(const float* __restrict__ adj,
                     unsigned char* __restrict__ a8,
                     const float* __restrict__ x,
                     const float* __restrict__ W,
                     unsigned char* __restrict__ hb8,
                     unsigned short* __restrict__ hnc_out) {
  __shared__ float xs[64 * 65];
  __shared__ unsigned short ht[64 * 72];
  int bid = blockIdx.x;

  if (bid >= 1024) {
    // ---- adj quantize part ----
    size_t base = ((size_t)(bid - 1024) * 256 + threadIdx.x) * 16;
    const float4* src = (const float4*)(adj + base);
    float4 q0 = src[0], q1 = src[1], q2 = src[2], q3 = src[3];
    int4 o;
    o.x = pk4_fp8(q0.x * ADJ_SCALE, q0.y * ADJ_SCALE, q0.z * ADJ_SCALE, q0.w * ADJ_SCALE);
    o.y = pk4_fp8(q1.x * ADJ_SCALE, q1.y * ADJ_SCALE, q1.z * ADJ_SCALE, q1.w * ADJ_SCALE);
    o.z = pk4_fp8(q2.x * ADJ_SCALE, q2.y * ADJ_SCALE, q2.z * ADJ_SCALE, q2.w * ADJ_SCALE);
    o.w = pk4_fp8(q3.x * ADJ_SCALE, q3.y * ADJ_SCALE, q3.z * ADJ_SCALE, q3.w * ADJ_SCALE);
    *(int4*)(a8 + base) = o;
    return;
  }

  // ---- layer-0 linear part ----
  int n0 = (bid & 63) * 64, c0 = (bid >> 6) * 64;

  for (int i = threadIdx.x; i < 1024; i += 256) {
    int bs = i >> 8, rem = i & 255, nr = rem >> 2, d4 = rem & 3;
    float4 v = *(const float4*)(
        x + ((size_t)(c0 / 16 + bs) * 4096 + n0 + nr) * 16 + d4 * 4);
    float* dst = xs + nr * 65 + bs * 16 + d4 * 4;
    dst[0] = v.x; dst[1] = v.y; dst[2] = v.z; dst[3] = v.w;
  }
  __syncthreads();

  int n_l = threadIdx.x & 63, b_l = threadIdx.x >> 6;   // b_l 0..3
  float xv[16];
#pragma unroll
  for (int d = 0; d < 16; ++d) xv[d] = xs[n_l * 65 + b_l * 16 + d];
  float accv[16];
#pragma unroll
  for (int e = 0; e < 16; ++e) accv[e] = 0.f;
#pragma unroll
  for (int d = 0; d < 16; ++d)
#pragma unroll
    for (int e = 0; e < 16; ++e) accv[e] += xv[d] * W[d * 16 + e];

  ushort8 h0, h1;
#pragma unroll
  for (int e = 0; e < 16; ++e) {
    float a = accv[e] > 0.f ? accv[e] : 0.2f * accv[e];
    unsigned short hv = f2bf(a);
    ht[(b_l * 16 + e) * 72 + n_l] = hv;
    if (e < 8) h0[e] = hv; else h1[e - 8] = hv;
  }
  unsigned short* ho = hnc_out + (size_t)(n0 + n_l) * 1024 + c0 + b_l * 16;
  *(ushort8*)(ho)     = h0;
  *(ushort8*)(ho + 8) = h1;
  __syncthreads();

  for (int i = threadIdx.x; i < 512; i += 256) {
    int row = i >> 3, ch = i & 7;
    const unsigned short* s = ht + row * 72 + ch * 8;
    int2 v;
    v.x = pk4_fp8(bf2f(s[0]), bf2f(s[1]), bf2f(s[2]), bf2f(s[3]));
    v.y = pk4_fp8(bf2f(s[4]), bf2f(s[5]), bf2f(s[6]), bf2f(s[7]));
    *(int2*)(hb8 + (size_t)(c0 + row) * 4096 + n0 + ch * 8) = v;
  }
}

// ---------------------------------------------------------------------------
// linear layers 1,2: u = p0 + p1 + h_nc (bf16); h = leaky_relu(u @ W);
// writes hb8 fp8 [c][n] (GEMM B operand, via LDS transpose) and h_nc bf16
// [n][c] (identity term for consumers).  Tile 64n x 64c, grid (64,16).
// ---------------------------------------------------------------------------
__global__ void linear_fuse(const unsigned short* __restrict__ pp,
                            const unsigned short* __restrict__ hnc_in,
                            const float* __restrict__ W,
                            unsigned char* __restrict__ hb8,
                            unsigned short* __restrict__ hnc_out) {
  __shared__ float xs[64 * 65];
  __shared__ unsigned short ht[64 * 72];
  int n0 = blockIdx.x * 64, c0 = blockIdx.y * 64;

  for (int i = threadIdx.x; i < 512; i += 256) {
    int row = i >> 3, ch = i & 7;
    size_t g = (size_t)(n0 + row) * 1024 + c0 + ch * 8;
    ushort8 a = *(const ushort8*)(pp + g);
    ushort8 b = *(const ushort8*)(pp + P_ELEMS + g);
    ushort8 c = *(const ushort8*)(hnc_in + g);
    float* dst = xs + row * 65 + ch * 8;
#pragma unroll
    for (int j = 0; j < 8; ++j) dst[j] = bf2f(a[j]) + bf2f(b[j]) + bf2f(c[j]);
  }
  __syncthreads();

  int n_l = threadIdx.x & 63, b_l = threadIdx.x >> 6;
  float xv[16];
#pragma unroll
  for (int d = 0; d < 16; ++d) xv[d] = xs[n_l * 65 + b_l * 16 + d];
  float accv[16];
#pragma unroll
  for (int e = 0; e < 16; ++e) accv[e] = 0.f;
#pragma unroll
  for (int d = 0; d < 16; ++d)
#pragma unroll
    for (int e = 0; e < 16; ++e) accv[e] += xv[d] * W[d * 16 + e];

  ushort8 h0, h1;
#pragma unroll
  for (int e = 0; e < 16; ++e) {
    float a = accv[e] > 0.f ? accv[e] : 0.2f * accv[e];
    unsigned short hv = f2bf(a);
    ht[(b_l * 16 + e) * 72 + n_l] = hv;
    if (e < 8) h0[e] = hv; else h1[e - 8] = hv;
  }
  unsigned short* ho = hnc_out + (size_t)(n0 + n_l) * 1024 + c0 + b_l * 16;
  *(ushort8*)(ho)     = h0;
  *(ushort8*)(ho + 8) = h1;
  __syncthreads();

  for (int i = threadIdx.x; i < 512; i += 256) {
    int row = i >> 3, ch = i & 7;
    const unsigned short* s = ht + row * 72 + ch * 8;
    int2 v;
    v.x = pk4_fp8(bf2f(s[0]), bf2f(s[1]), bf2f(s[2]), bf2f(s[3]));
    v.y = pk4_fp8(bf2f(s[4]), bf2f(s[5]), bf2f(s[6]), bf2f(s[7]));
    *(int2*)(hb8 + (size_t)(c0 + row) * 4096 + n0 + ch * 8) = v;
  }
}

// ---------------------------------------------------------------------------
// final: out fp32 (b,n,d) = p0 + p1 + h_nc   (all stored [n][c] bf16)
// ---------------------------------------------------------------------------
__global__ void add_out(const unsigned short* __restrict__ pp,
                        const unsigned short* __restrict__ hnc,
                        float* __restrict__ out) {
  int gid = blockIdx.x * 256 + threadIdx.x;      // 0..524287
  int n = gid >> 7, c8 = (gid & 127) * 8;
  size_t g = (size_t)n * 1024 + c8;
  ushort8 a = *(const ushort8*)(pp + g);
  ushort8 b = *(const ushort8*)(pp + P_ELEMS + g);
  ushort8 h = *(const ushort8*)(hnc + g);
  float v[8];
#pragma unroll
  for (int j = 0; j < 8; ++j) v[j] = bf2f(a[j]) + bf2f(b[j]) + bf2f(h[j]);
  int bb = c8 >> 4, d0 = c8 & 15;                // d0 = 0 or 8
  float* o = out + (size_t)bb * 65536 + n * 16 + d0;
  *(float4*)(o)     = float4{v[0], v[1], v[2], v[3]};
  *(float4*)(o + 4) = float4{v[4], v[5], v[6], v[7]};
}

// ---------------------------------------------------------------------------
// p[ks][n][c] = (adj8[n0..][k] * hb8[c0..][k]) / 4096   (one K-half per block)
// MX-scaled fp8 MFMA 16x16x128, unit scales.  Grid 512 = 32mt x 8ct x 2ks,
// xcd = lin&7 (adj8 slice L2 locality).
// 512 THREADS: 8 waves = 2(wm) x 4(wn), wave tile 64n x 32c, acc[4][2].
// -> 2 blocks/CU x 8 waves = 16 waves/CU = 4/SIMD in 2 INDEPENDENT barrier
// groups: the per-iter convoy (barrier -> ds_read burst -> lgkm -> MFMA)
// of one group interleaves with the other group's, and the 2nd same-group
// wave on each SIMD fills lgkm gaps.  16 iters (min block-iters/CU = 32).
// K-loop: dbuf, XOR chunk swizzle, counted vmcnt(4) + raw s_barrier,
// stage(it+2) after the post-compute barrier, setprio around MFMA.
// Staging per wave per tile: A rows w*16..+15 (2 insts) + B same (2 insts).
// ---------------------------------------------------------------------------
__global__ __launch_bounds__(512, 4)
void gemm_f8(const unsigned char* __restrict__ A,
             const unsigned char* __restrict__ B8,
             unsigned short* __restrict__ pp) {
  const int K = 4096;
  __shared__ unsigned char a_s[2][128 * 128];   // 2 x 16 KB
  __shared__ unsigned char b_s[2][128 * 128];   // 2 x 16 KB

  int tid = threadIdx.x, wave = tid >> 6, lane = tid & 63;

  int lin = blockIdx.x;
  int xcd = lin & 7, g = lin >> 3;
  int mth = g & 3, ct = (g >> 2) & 7, ks = g >> 5;   // ks in {0,1}
  int mt = mth * 8 + xcd;
  int n0 = mt * 128, c0 = ct * 128;
  int kbase = ks * 2048;

  // staging: wave w covers rows w*16..w*16+15 (2 insts each operand)
  int l8 = lane >> 3, lc = lane & 7;
  int swc = lc ^ l8;                 // logical chunk fetched into phys lc
  const unsigned char* gA[2];
  const unsigned char* gB[2];
#pragma unroll
  for (int j = 0; j < 2; ++j) {
    int r = wave * 16 + j * 8 + l8;
    gA[j] = A  + (size_t)(n0 + r) * K + kbase + swc * 16;
    gB[j] = B8 + (size_t)(c0 + r) * K + kbase + swc * 16;
  }

  int i16 = lane & 15, q = lane >> 4;
  int wm = wave >> 2, wn = wave & 3;      // 2 x 4
  int sw7 = i16 & 7;
  int pc0 = ((2 * q) ^ sw7) * 16;        // phys offset of logical chunk 2q
  int pc1 = ((2 * q + 1) ^ sw7) * 16;    // phys offset of logical chunk 2q+1

#define STAGE(buf, it)                                                \
  do {                                                                \
    int k0_ = (it) * 128;                                             \
    _Pragma("unroll")                                                 \
    for (int j = 0; j < 2; ++j) {                                     \
      GLOAD_LDS16(gA[j] + k0_, a_s[buf] + (wave * 16 + j * 8) * 128); \
      GLOAD_LDS16(gB[j] + k0_, b_s[buf] + (wave * 16 + j * 8) * 128); \
    }                                                                 \
  } while (0)

#define COMPUTE(buf)                                                  \
  do {                                                                \
    i32x8 bv[2];                                                      \
    _Pragma("unroll")                                                 \
    for (int u = 0; u < 2; ++u) {                                     \
      const unsigned char* bp = b_s[buf] + (wn * 32 + u * 16 + i16) * 128; \
      i32x4 blo = *(const i32x4*)(bp + pc0);                          \
      i32x4 bhi = *(const i32x4*)(bp + pc1);                          \
      bv[u] = __builtin_shufflevector(blo, bhi, 0, 1, 2, 3, 4, 5, 6, 7); \
    }                                                                 \
    __builtin_amdgcn_s_setprio(1);                                    \
    _Pragma("unroll")                                                 \
    for (int t = 0; t < 4; ++t) {                                     \
      const unsigned char* ap = a_s[buf] + (wm * 64 + t * 16 + i16) * 128; \
      i32x4 alo = *(const i32x4*)(ap + pc0);                          \
      i32x4 ahi = *(const i32x4*)(ap + pc1);                          \
      i32x8 av = __builtin_shufflevector(alo, ahi, 0, 1, 2, 3, 4, 5, 6, 7); \
      _Pragma("unroll")                                               \
      for (int u = 0; u < 2; ++u)                                     \
        acc[t][u] = __builtin_amdgcn_mfma_scale_f32_16x16x128_f8f6f4( \
            av, bv[u], acc[t][u], 0, 0, 0, SCALE_ONE, 0, SCALE_ONE);  \
    }                                                                 \
    __builtin_amdgcn_s_setprio(0);                                    \
  } while (0)

#define WAITVM4() asm volatile("s_waitcnt vmcnt(4)" ::: "memory")
#define WAITVM0() asm volatile("s_waitcnt vmcnt(0)" ::: "memory")
#define BARX() do { asm volatile("" ::: "memory");                    \
                    __builtin_amdgcn_s_barrier();                     \
                    asm volatile("" ::: "memory"); } while (0)

  f32x4 acc[4][2] = {};

  // prologue: two tiles in flight (8 loads/wave)
  STAGE(0, 0);
  STAGE(1, 1);

  for (int itb = 0; itb < 14; itb += 2) {
    WAITVM4(); BARX(); COMPUTE(0); BARX(); STAGE(0, itb + 2);
    WAITVM4(); BARX(); COMPUTE(1); BARX(); STAGE(1, itb + 3);
  }
  WAITVM4(); BARX(); COMPUTE(0);           // it = 14 (stage15 still flying)
  WAITVM0(); BARX(); COMPUTE(1);           // it = 15

#undef STAGE
#undef COMPUTE
#undef WAITVM4
#undef WAITVM0
#undef BARX

  // epilogue: descale + bf16 store of this K-half's partial
  unsigned short* dst = pp + (size_t)ks * P_ELEMS;
#pragma unroll
  for (int t = 0; t < 4; ++t)
#pragma unroll
    for (int u = 0; u < 2; ++u)
#pragma unroll
      for (int i = 0; i < 4; ++i) {
        int n_g = n0 + wm * 64 + t * 16 + q * 4 + i;
        int c_g = c0 + wn * 32 + u * 16 + i16;
        dst[(size_t)n_g * 1024 + c_g] = f2bf(acc[t][u][i] * ADJ_DESCALE);
      }
}

// ---------------------------------------------------------------------------
extern "C" void kernel_launch(void* const* d_in, const int* in_sizes, int n_in,
                              void* d_out, int out_size, void* d_ws, size_t ws_size,
                              hipStream_t stream) {
  const float* x   = (const float*)d_in[0];
  const float* adj = (const float*)d_in[1];
  // d_in[2] = Identity (handled as the +h_nc term)
  const float* W0  = (const float*)d_in[3];
  const float* W1  = (const float*)d_in[4];
  const float* W2  = (const float*)d_in[5];
  float* out = (float*)d_out;

  char* ws = (char*)d_ws;
  unsigned char*  adj8 = (unsigned char*)ws;                   // 16 MiB
  unsigned char*  hb8  = (unsigned char*)(ws + 16777216);      //  4 MiB
  unsigned short* hnc  = (unsigned short*)(ws + 20971520);     //  8 MiB
  unsigned short* pp   = (unsigned short*)(ws + 29360128);     // p0|p1 16 MiB

  // layer 0 linear + adj quantize fused (independent, both memory-bound)
  prep<<<5120, 256, 0, stream>>>(adj, adj8, x, W0, hb8, hnc);
  gemm_f8<<<512, 512, 0, stream>>>(adj8, hb8, pp);
  // layer 1
  linear_fuse<<<dim3(64, 16), 256, 0, stream>>>(pp, hnc, W1, hb8, hnc);
  gemm_f8<<<512, 512, 0, stream>>>(adj8, hb8, pp);
  // layer 2
  linear_fuse<<<dim3(64, 16), 256, 0, stream>>>(pp, hnc, W2, hb8, hnc);
  gemm_f8<<<512, 512, 0, stream>>>(adj8, hb8, pp);
  add_out<<<2048, 256, 0, stream>>>(pp, hnc, out);
}